// Round 1
// baseline (658.222 us; speedup 1.0000x reference)
//
#include <hip/hip_runtime.h>
#include <math.h>

// Problem constants
constexpr int Bc  = 4;
constexpr int Sc  = 2048;
constexpr int Dc  = 512;
constexpr int Hc  = 8;
constexpr int DKc = 64;
constexpr int Mc  = Bc * Sc;   // 8192 rows

constexpr float SCALE_Q = 0.180336880111120426f;   // (1/8) * log2(e): /H quirk + exp2 base

typedef __attribute__((ext_vector_type(8)))  short s16x8;   // 8 bf16 MFMA frag
typedef __attribute__((ext_vector_type(4)))  float f32x4;   // 16x16 accumulator
typedef __attribute__((ext_vector_type(16))) float f32x16;  // 32x32 accumulator

__device__ __forceinline__ unsigned short f2bf(float f) {
    __bf16 h = (__bf16)f;                 // RNE convert
    return __builtin_bit_cast(unsigned short, h);
}

__device__ __forceinline__ float fexp2(float x) {
#if __has_builtin(__builtin_amdgcn_exp2f)
    return __builtin_amdgcn_exp2f(x);
#else
    return __expf(x * 0.6931471805599453f);
#endif
}

__device__ __forceinline__ uint4 pack8(float4 a, float4 b) {
    uint4 u;
    u.x = (unsigned)f2bf(a.x) | ((unsigned)f2bf(a.y) << 16);
    u.y = (unsigned)f2bf(a.z) | ((unsigned)f2bf(a.w) << 16);
    u.z = (unsigned)f2bf(b.x) | ((unsigned)f2bf(b.y) << 16);
    u.w = (unsigned)f2bf(b.z) | ((unsigned)f2bf(b.w) << 16);
    return u;
}

// ---------------------------------------------------------------------------
// mask [B,1,S,S] int32 -> keep-bit words: bit j of word w == (mask[w*64+j]!=0)
// ---------------------------------------------------------------------------
__global__ __launch_bounds__(256)
void pack_mask(const int* __restrict__ mask, unsigned long long* __restrict__ out,
               int nwords)
{
    int gw   = (blockIdx.x * blockDim.x + threadIdx.x) >> 6;
    int lane = threadIdx.x & 63;
    int nw   = (gridDim.x * blockDim.x) >> 6;
    for (int w0 = gw * 4; w0 < nwords; w0 += nw * 4) {
        int vals[4];
#pragma unroll
        for (int c = 0; c < 4; ++c)
            vals[c] = mask[(size_t)(w0 + c) * 64 + lane];
#pragma unroll
        for (int c = 0; c < 4; ++c) {
            unsigned long long bits = __ballot(vals[c] != 0);
            if (lane == 0) out[w0 + c] = bits;
        }
    }
}

// ---------------------------------------------------------------------------
// fp32 -> bf16 elementwise, 4 tensors (blockIdx.y selects), n4 float4s each
// ---------------------------------------------------------------------------
__global__ __launch_bounds__(256)
void cvt4(const float* __restrict__ i0, const float* __restrict__ i1,
          const float* __restrict__ i2, const float* __restrict__ i3,
          unsigned short* __restrict__ o0, unsigned short* __restrict__ o1,
          unsigned short* __restrict__ o2, unsigned short* __restrict__ o3,
          int n4)
{
    const float* in; unsigned short* out;
    switch (blockIdx.y) {
        case 0: in = i0; out = o0; break;
        case 1: in = i1; out = o1; break;
        case 2: in = i2; out = o2; break;
        default: in = i3; out = o3; break;
    }
    int i = blockIdx.x * 256 + threadIdx.x;
    if (i < n4) {
        float4 v = ((const float4*)in)[i];
        ushort4 r;
        r.x = f2bf(v.x); r.y = f2bf(v.y); r.z = f2bf(v.z); r.w = f2bf(v.w);
        ((ushort4*)out)[i] = r;
    }
}

// ---------------------------------------------------------------------------
// 128x64-tile bf16-MFMA GEMM (unchanged — attn is the focus this round)
// ---------------------------------------------------------------------------
template<bool XBF>
__global__ __launch_bounds__(256, 3)
void gemm128(const void* __restrict__ x0, const void* __restrict__ x1,
             const void* __restrict__ x2,
             const unsigned short* __restrict__ w0, const unsigned short* __restrict__ w1,
             const unsigned short* __restrict__ w2,
             const float* __restrict__ b0, const float* __restrict__ b1,
             const float* __restrict__ b2,
             void* __restrict__ o0v, void* __restrict__ o1v, void* __restrict__ o2v,
             float s0, float s1, float s2, int m0, int m1, int m2)
{
    const void* Xv; const unsigned short* W; const float* bias; void* outv;
    float scale; int mode;
    switch (blockIdx.z) {
        case 0:  Xv = x0; W = w0; bias = b0; outv = o0v; scale = s0; mode = m0; break;
        case 1:  Xv = x1; W = w1; bias = b1; outv = o1v; scale = s1; mode = m1; break;
        default: Xv = x2; W = w2; bias = b2; outv = o2v; scale = s2; mode = m2; break;
    }

    __shared__ unsigned short Xs[2][128 * 64];
    __shared__ unsigned short Ws[2][64 * 64];

    const int tid = threadIdx.x;
    const int w = tid >> 6, lane = tid & 63, ln = lane & 15, qd = lane >> 4;
    const int wm = (w >> 1) * 64, wn = (w & 1) * 32;
    const int row0 = blockIdx.x * 128, col0 = blockIdx.y * 64;

    f32x4 acc[4][2];
#pragma unroll
    for (int mt = 0; mt < 4; ++mt)
#pragma unroll
        for (int nt = 0; nt < 2; ++nt) acc[mt][nt] = f32x4{0.f, 0.f, 0.f, 0.f};

    uint4 xb[4], wr[2];
    auto load = [&](int k0) {
#pragma unroll
        for (int c = 0; c < 4; ++c) {
            int u = tid + c * 256, r = u >> 3, c8 = u & 7;
            if (XBF) {
                xb[c] = *(const uint4*)((const unsigned short*)Xv +
                                        (size_t)(row0 + r) * 512 + k0 + c8 * 8);
            } else {
                const float* xp = (const float*)Xv + (size_t)(row0 + r) * 512 + k0 + c8 * 8;
                xb[c] = pack8(*(const float4*)xp, *(const float4*)(xp + 4));
            }
        }
#pragma unroll
        for (int c = 0; c < 2; ++c) {
            int u = tid + c * 256, r = u >> 3, c8 = u & 7;
            wr[c] = *(const uint4*)(W + (size_t)(col0 + r) * 512 + k0 + c8 * 8);
        }
    };
    auto store = [&](int buf) {
#pragma unroll
        for (int c = 0; c < 4; ++c) {
            int u = tid + c * 256, r = u >> 3, c8 = u & 7;
            *(uint4*)&Xs[buf][r * 64 + ((c8 ^ (r & 7)) * 8)] = xb[c];
        }
#pragma unroll
        for (int c = 0; c < 2; ++c) {
            int u = tid + c * 256, r = u >> 3, c8 = u & 7;
            *(uint4*)&Ws[buf][r * 64 + ((c8 ^ (r & 7)) * 8)] = wr[c];
        }
    };

    load(0);
    store(0);
    for (int k0 = 0; k0 < 512; k0 += 64) {
        const int buf = (k0 >> 6) & 1;
        __syncthreads();
        if (k0 + 64 < 512) load(k0 + 64);
#pragma unroll
        for (int kc = 0; kc < 2; ++kc) {
            s16x8 af[4], bfr[2];
#pragma unroll
            for (int mt = 0; mt < 4; ++mt) {
                int r = wm + mt * 16 + ln;
                af[mt] = *(const s16x8*)&Xs[buf][r * 64 + (((kc * 4 + qd) ^ (ln & 7)) * 8)];
            }
#pragma unroll
            for (int nt = 0; nt < 2; ++nt) {
                int r = wn + nt * 16 + ln;
                bfr[nt] = *(const s16x8*)&Ws[buf][r * 64 + (((kc * 4 + qd) ^ (ln & 7)) * 8)];
            }
#pragma unroll
            for (int mt = 0; mt < 4; ++mt)
#pragma unroll
                for (int nt = 0; nt < 2; ++nt)
                    acc[mt][nt] = __builtin_amdgcn_mfma_f32_16x16x32_bf16(
                        af[mt], bfr[nt], acc[mt][nt], 0, 0, 0);
        }
        if (k0 + 64 < 512) store(buf ^ 1);
    }

#pragma unroll
    for (int nt = 0; nt < 2; ++nt) {
        const int n = col0 + wn + nt * 16 + ln;
        const float bz = bias[n];
#pragma unroll
        for (int mt = 0; mt < 4; ++mt) {
            const int mbase = row0 + wm + mt * 16 + qd * 4;
            if (mode == 0) {
                float* o = (float*)outv;
#pragma unroll
                for (int r = 0; r < 4; ++r)
                    o[(size_t)(mbase + r) * 512 + n] = acc[mt][nt][r] + bz;
            } else if (mode == 1) {
                unsigned short* o = (unsigned short*)outv;
                const int h = n >> 6, dk = n & 63;
#pragma unroll
                for (int r = 0; r < 4; ++r) {
                    int m = mbase + r, b = m >> 11, s = m & 2047;
                    o[((size_t)(b * Hc + h) * Sc + s) * 64 + dk] =
                        f2bf((acc[mt][nt][r] + bz) * scale);
                }
            } else {
                unsigned short* o = (unsigned short*)outv;
                const int h = n >> 6, dk = n & 63;
                const int b = mbase >> 11, sb = mbase & 2047;
                const int ss = (sb & ~12) | ((sb & 4) << 1) | ((sb & 8) >> 1); // swap bits 2,3
                ushort4 pk;
                pk.x = f2bf((acc[mt][nt][0] + bz) * scale);
                pk.y = f2bf((acc[mt][nt][1] + bz) * scale);
                pk.z = f2bf((acc[mt][nt][2] + bz) * scale);
                pk.w = f2bf((acc[mt][nt][3] + bz) * scale);
                *(ushort4*)(o + ((size_t)(b * Hc + h) * 64 + dk) * Sc + ss) = pk;
            }
        }
    }
}

// ---------------------------------------------------------------------------
// Split-K bf16 32x32x16-MFMA flash attention, max-free softmax, DUAL Q-TILE,
// 4-WAY KEY SPLIT. Grid (S/128, B*H) = 512 blocks; 512 thr = 8 waves =
// 2 q-groups x 4 key-quarters. Wave (kh,g): q rows qA = q0+g*64+ln, qB=qA+32;
// keys kh*512..+512 in 16 tiles of 32.
//
// r8 counters: MfmaUtil 11%, VALU 26%, HBM 8%, Occupancy 19% -> latency
// bound with the grid (512 blocks = 2 blocks/CU = 8 waves/CU) as the cap,
// NOT registers (VGPR=108, 256-budget unused). This version doubles TLP to
// 16 waves/CU (4/SIMD) by doubling waves/block, grid unchanged.
// LDS: 4 groups x (4KB K + 4KB V) x 2 buf = 64KB -> exactly 2 blocks/CU.
//
// Bank conflicts (8.1M cyc/dispatch, ~10 cyc per LDS op on the MFMA dep
// path): the padded strides (72/40 shorts = 4-way read, 8-way write) are
// replaced by XOR swizzles with conflict-free read AND write groups:
//   K slot(r,c)  = r*8  + (c ^ (r&7))      (same swizzle the GEMM uses)
//   V slot(dv,c) = c*64 + (dv ^ (c<<1))    (chunk-major)
// Math proven r4-r7: p=exp2(masked s'), masked->0; PV B-frags are the lane's
// own p regs (V key axis swap23-permuted at projection); linear combine of
// the 4 key-quarter partials through a [128][68]-f32 LDS region (stride 68
// = 4 mod 32 -> conflict-free), 4 serial phases, once per block.
// ---------------------------------------------------------------------------
__global__ __launch_bounds__(512, 4)
void attn_mfma(const unsigned short* __restrict__ qh, const unsigned short* __restrict__ kh,
               const unsigned short* __restrict__ vt, const unsigned* __restrict__ mbits,
               unsigned short* __restrict__ ctx)
{
    __shared__ uint4 smem4[2][2048];   // 2 x 32768 B = 64 KB

    const int bh = blockIdx.y, b = bh >> 3, h = bh & 7;
    const int q0 = blockIdx.x * 128;
    const int tid = threadIdx.x;
    const int w = tid >> 6;
    const int kh_ = w >> 1;          // key quarter 0..3
    const int g = w & 1;             // q-group
    const int lane = tid & 63, ln = lane & 31, hf = lane >> 5;
    const int qrA = q0 + g * 64 + ln;
    const int qrB = qrA + 32;

    const int st = g * 64 + lane;    // staging id 0..127 within kh-group (2 waves)

    // Q B-frags for both tiles, resident
    s16x8 qfA[4], qfB[4];
    {
        const unsigned short* qpA = qh + ((size_t)bh * Sc + qrA) * 64 + hf * 8;
        const unsigned short* qpB = qh + ((size_t)bh * Sc + qrB) * 64 + hf * 8;
#pragma unroll
        for (int kc = 0; kc < 4; ++kc) {
            qfA[kc] = *(const s16x8*)(qpA + kc * 16);
            qfB[kc] = *(const s16x8*)(qpB + kc * 16);
        }
    }

    f32x16 oA0, oA1, oB0, oB1;
#pragma unroll
    for (int r = 0; r < 16; ++r) { oA0[r] = 0.f; oA1[r] = 0.f; oB0[r] = 0.f; oB1[r] = 0.f; }
    float lrA = 0.f, lrB = 0.f;

    const unsigned* mrA = mbits + ((size_t)b * Sc + qrA) * (Sc / 32);
    const unsigned* mrB = mbits + ((size_t)b * Sc + qrB) * (Sc / 32);
    const unsigned short* kbase = kh + (size_t)bh * Sc * 64;
    const unsigned short* vbase = vt + (size_t)bh * 64 * Sc;

    const int kt0 = kh_ * 512;
    uint4 pre[4];
    auto load_tile = [&](int kt) {
#pragma unroll
        for (int c = 0; c < 2; ++c) {       // K: 32 rows x 8 chunks
            int idx = st + c * 128, r = idx >> 3, cc = idx & 7;
            pre[c] = *(const uint4*)(kbase + (size_t)(kt + r) * 64 + cc * 8);
        }
#pragma unroll
        for (int c = 2; c < 4; ++c) {       // V: 64 dv x 4 chunks (32 keys)
            int j = st + (c - 2) * 128, dv = j >> 2, cc = j & 3;
            pre[c] = *(const uint4*)(vbase + (size_t)dv * Sc + kt + cc * 8);
        }
    };
    auto store_tile = [&](int buf) {
        unsigned short* Ks = (unsigned short*)smem4[buf] + kh_ * 4096;  // 8 KB / group
        unsigned short* Vs = Ks + 2048;
#pragma unroll
        for (int c = 0; c < 2; ++c) {       // K swizzle: slot = r*8 + (cc ^ (r&7))
            int idx = st + c * 128, r = idx >> 3, cc = idx & 7;
            *(uint4*)&Ks[r * 64 + ((cc ^ (r & 7)) * 8)] = pre[c];
        }
#pragma unroll
        for (int c = 2; c < 4; ++c) {       // V swizzle: slot = cc*64 + (dv ^ (cc<<1))
            int j = st + (c - 2) * 128, dv = j >> 2, cc = j & 3;
            *(uint4*)&Vs[(cc * 64 + (dv ^ (cc << 1))) * 8] = pre[c];
        }
    };

    load_tile(kt0);
    unsigned mwnA = mrA[kt0 >> 5], mwnB = mrB[kt0 >> 5];
    store_tile(0);

    for (int i = 0; i < 16; ++i) {
        const int kt = kt0 + i * 32;
        const int buf = i & 1;
        __syncthreads();
        const unsigned mwA = mwnA, mwB = mwnB;
        if (i < 15) {
            load_tile(kt + 32);
            mwnA = mrA[(kt + 32) >> 5];
            mwnB = mrB[(kt + 32) >> 5];
        }

        const unsigned short* Ks = (const unsigned short*)smem4[buf] + kh_ * 4096;
        const unsigned short* Vs = Ks + 2048;

        // ---- S^T[key][q] = K · Q^T, both q-tiles share kf reads
        f32x16 svA, svB;
#pragma unroll
        for (int r = 0; r < 16; ++r) { svA[r] = 0.f; svB[r] = 0.f; }
#pragma unroll
        for (int kc = 0; kc < 4; ++kc) {
            s16x8 kf = *(const s16x8*)&Ks[ln * 64 + ((((kc << 1) | hf) ^ (ln & 7)) * 8)];
            svA = __builtin_amdgcn_mfma_f32_32x32x16_bf16(kf, qfA[kc], svA, 0, 0, 0);
            svB = __builtin_amdgcn_mfma_f32_32x32x16_bf16(kf, qfB[kc], svB, 0, 0, 0);
        }

        // ---- mask + exp2 (no max: scores bounded), pack to bf16 pairs
        float psA = 0.f, psB = 0.f;
        unsigned puA[8], puB[8];
#pragma unroll
        for (int r = 0; r < 16; r += 2) {
            int key0 = (r & 3) + 8 * (r >> 2) + 4 * hf;
            int key1 = ((r + 1) & 3) + 8 * ((r + 1) >> 2) + 4 * hf;
            float a0 = ((mwA >> key0) & 1u) ? svA[r]     : -1e9f;
            float a1 = ((mwA >> key1) & 1u) ? svA[r + 1] : -1e9f;
            float b0 = ((mwB >> key0) & 1u) ? svB[r]     : -1e9f;
            float b1 = ((mwB >> key1) & 1u) ? svB[r + 1] : -1e9f;
            float pA0 = fexp2(a0), pA1 = fexp2(a1);
            float pB0 = fexp2(b0), pB1 = fexp2(b1);
            psA += pA0 + pA1;  psB += pB0 + pB1;
            puA[r >> 1] = (unsigned)f2bf(pA0) | ((unsigned)f2bf(pA1) << 16);
            puB[r >> 1] = (unsigned)f2bf(pB0) | ((unsigned)f2bf(pB1) << 16);
        }
        lrA += psA;  lrB += psB;

        // ---- ctx^T[dv][q] += V · P^T, both q-tiles share V reads
#pragma unroll
        for (int kc = 0; kc < 2; ++kc) {
            uint4 ua; ua.x = puA[4*kc]; ua.y = puA[4*kc+1]; ua.z = puA[4*kc+2]; ua.w = puA[4*kc+3];
            uint4 ub; ub.x = puB[4*kc]; ub.y = puB[4*kc+1]; ub.z = puB[4*kc+2]; ub.w = puB[4*kc+3];
            s16x8 pfA = __builtin_bit_cast(s16x8, ua);
            s16x8 pfB = __builtin_bit_cast(s16x8, ub);
            const int cc = (kc << 1) | hf;
            s16x8 v0  = *(const s16x8*)&Vs[(cc * 64 + (ln ^ (cc << 1))) * 8];
            s16x8 v1  = *(const s16x8*)&Vs[(cc * 64 + ((32 + ln) ^ (cc << 1))) * 8];
            oA0 = __builtin_amdgcn_mfma_f32_32x32x16_bf16(v0, pfA, oA0, 0, 0, 0);
            oB0 = __builtin_amdgcn_mfma_f32_32x32x16_bf16(v0, pfB, oB0, 0, 0, 0);
            oA1 = __builtin_amdgcn_mfma_f32_32x32x16_bf16(v1, pfA, oA1, 0, 0, 0);
            oB1 = __builtin_amdgcn_mfma_f32_32x32x16_bf16(v1, pfB, oB1, 0, 0, 0);
        }

        if (i < 15) store_tile(buf ^ 1);
    }

    // l per-hf partial -> full
    lrA += __shfl_xor(lrA, 32);
    lrB += __shfl_xor(lrB, 32);

    // ---- cross-quarter combine (linear): kh3 writes, kh2/kh1 add, kh0 finishes.
    // Region [128][68] f32 = 34816 B overlaying the staging buffers.
    __syncthreads();
    float* cs = (float*)smem4[0];
    float* my = cs + (size_t)(g * 64 + lane) * 68;

    if (kh_ == 3) {
#pragma unroll
        for (int r = 0; r < 4; ++r) {
            *(float4*)(my + 4 * r)      = make_float4(oA0[4*r], oA0[4*r+1], oA0[4*r+2], oA0[4*r+3]);
            *(float4*)(my + 16 + 4 * r) = make_float4(oA1[4*r], oA1[4*r+1], oA1[4*r+2], oA1[4*r+3]);
            *(float4*)(my + 32 + 4 * r) = make_float4(oB0[4*r], oB0[4*r+1], oB0[4*r+2], oB0[4*r+3]);
            *(float4*)(my + 48 + 4 * r) = make_float4(oB1[4*r], oB1[4*r+1], oB1[4*r+2], oB1[4*r+3]);
        }
        my[64] = lrA;
        my[65] = lrB;
    }
    __syncthreads();
#pragma unroll
    for (int ph = 2; ph >= 1; --ph) {
        if (kh_ == ph) {
#pragma unroll
            for (int r = 0; r < 4; ++r) {
                float4 t;
                t = *(float4*)(my + 4 * r);
                t.x += oA0[4*r]; t.y += oA0[4*r+1]; t.z += oA0[4*r+2]; t.w += oA0[4*r+3];
                *(float4*)(my + 4 * r) = t;
                t = *(float4*)(my + 16 + 4 * r);
                t.x += oA1[4*r]; t.y += oA1[4*r+1]; t.z += oA1[4*r+2]; t.w += oA1[4*r+3];
                *(float4*)(my + 16 + 4 * r) = t;
                t = *(float4*)(my + 32 + 4 * r);
                t.x += oB0[4*r]; t.y += oB0[4*r+1]; t.z += oB0[4*r+2]; t.w += oB0[4*r+3];
                *(float4*)(my + 32 + 4 * r) = t;
                t = *(float4*)(my + 48 + 4 * r);
                t.x += oB1[4*r]; t.y += oB1[4*r+1]; t.z += oB1[4*r+2]; t.w += oB1[4*r+3];
                *(float4*)(my + 48 + 4 * r) = t;
            }
            my[64] += lrA;
            my[65] += lrB;
        }
        __syncthreads();
    }
    if (kh_ == 0) {
        lrA += my[64];
        lrB += my[65];
        const float invA = 1.f / lrA, invB = 1.f / lrB;
#pragma unroll
        for (int r = 0; r < 4; ++r) {
            float4 a0 = *(const float4*)(my + 4 * r);
            float4 a1 = *(const float4*)(my + 16 + 4 * r);
            float4 b0 = *(const float4*)(my + 32 + 4 * r);
            float4 b1 = *(const float4*)(my + 48 + 4 * r);
            oA0[4*r]   = (oA0[4*r]   + a0.x) * invA; oA0[4*r+1] = (oA0[4*r+1] + a0.y) * invA;
            oA0[4*r+2] = (oA0[4*r+2] + a0.z) * invA; oA0[4*r+3] = (oA0[4*r+3] + a0.w) * invA;
            oA1[4*r]   = (oA1[4*r]   + a1.x) * invA; oA1[4*r+1] = (oA1[4*r+1] + a1.y) * invA;
            oA1[4*r+2] = (oA1[4*r+2] + a1.z) * invA; oA1[4*r+3] = (oA1[4*r+3] + a1.w) * invA;
            oB0[4*r]   = (oB0[4*r]   + b0.x) * invB; oB0[4*r+1] = (oB0[4*r+1] + b0.y) * invB;
            oB0[4*r+2] = (oB0[4*r+2] + b0.z) * invB; oB0[4*r+3] = (oB0[4*r+3] + b0.w) * invB;
            oB1[4*r]   = (oB1[4*r]   + b1.x) * invB; oB1[4*r+1] = (oB1[4*r+1] + b1.y) * invB;
            oB1[4*r+2] = (oB1[4*r+2] + b1.z) * invB; oB1[4*r+3] = (oB1[4*r+3] + b1.w) * invB;
        }
        // ctx bf16 [B,S,D]; dv = 8*gg + 4*hf + t (+32 for the *1 half)
        unsigned short* opA = ctx + ((size_t)(b * Sc + qrA)) * 512 + h * 64;
        unsigned short* opB = ctx + ((size_t)(b * Sc + qrB)) * 512 + h * 64;
#pragma unroll
        for (int gg = 0; gg < 4; ++gg) {
            ushort4 a, c;
            a.x = f2bf(oA0[gg*4+0]); a.y = f2bf(oA0[gg*4+1]);
            a.z = f2bf(oA0[gg*4+2]); a.w = f2bf(oA0[gg*4+3]);
            c.x = f2bf(oA1[gg*4+0]); c.y = f2bf(oA1[gg*4+1]);
            c.z = f2bf(oA1[gg*4+2]); c.w = f2bf(oA1[gg*4+3]);
            *(ushort4*)(opA + 8 * gg + 4 * hf)      = a;
            *(ushort4*)(opA + 32 + 8 * gg + 4 * hf) = c;
            ushort4 d, e;
            d.x = f2bf(oB0[gg*4+0]); d.y = f2bf(oB0[gg*4+1]);
            d.z = f2bf(oB0[gg*4+2]); d.w = f2bf(oB0[gg*4+3]);
            e.x = f2bf(oB1[gg*4+0]); e.y = f2bf(oB1[gg*4+1]);
            e.z = f2bf(oB1[gg*4+2]); e.w = f2bf(oB1[gg*4+3]);
            *(ushort4*)(opB + 8 * gg + 4 * hf)      = d;
            *(ushort4*)(opB + 32 + 8 * gg + 4 * hf) = e;
        }
    }
}

// ---------------------------------------------------------------------------
extern "C" void kernel_launch(void* const* d_in, const int* in_sizes, int n_in,
                              void* d_out, int out_size, void* d_ws, size_t ws_size,
                              hipStream_t stream)
{
    (void)in_sizes; (void)n_in; (void)out_size; (void)ws_size;

    const float* q    = (const float*)d_in[0];
    const float* k    = (const float*)d_in[1];
    const float* v    = (const float*)d_in[2];
    const int*   mask = (const int*)  d_in[3];
    const float* Wq   = (const float*)d_in[4];
    const float* bq   = (const float*)d_in[5];
    const float* Wk   = (const float*)d_in[6];
    const float* bk   = (const float*)d_in[7];
    const float* Wv   = (const float*)d_in[8];
    const float* bv   = (const float*)d_in[9];
    const float* Wo   = (const float*)d_in[10];
    const float* bo   = (const float*)d_in[11];
    float* out = (float*)d_out;

    // workspace carve; TEN = 4,194,304 elems
    constexpr size_t TEN = (size_t)Bc * Hc * Sc * DKc;
    char* p = (char*)d_ws;
    unsigned short* wqb   = (unsigned short*)p;  p += (size_t)Dc * Dc * 2;  // 0.5 MB
    unsigned short* wkb   = (unsigned short*)p;  p += (size_t)Dc * Dc * 2;
    unsigned short* wvb   = (unsigned short*)p;  p += (size_t)Dc * Dc * 2;
    unsigned short* wob   = (unsigned short*)p;  p += (size_t)Dc * Dc * 2;
    unsigned short* qh_bf = (unsigned short*)p;  p += TEN * 2;              // 8 MB
    unsigned short* kh_bf = (unsigned short*)p;  p += TEN * 2;
    unsigned short* vt_bf = (unsigned short*)p;  p += TEN * 2;
    unsigned short* ctx   = (unsigned short*)p;  p += TEN * 2;
    unsigned long long* mb64 = (unsigned long long*)p;                      // 2 MB

    const int nwords = Bc * Sc * (Sc / 64);   // 262144

    dim3 bb(256);

    pack_mask<<<dim3(16384), bb, 0, stream>>>(mask, mb64, nwords);
    cvt4<<<dim3(Dc * Dc / 4 / 256, 4), bb, 0, stream>>>(Wq, Wk, Wv, Wo, wqb, wkb, wvb, wob,
                                                        Dc * Dc / 4);
    // merged Q/K/V projections: one dispatch, 1536 blocks, 3 blocks/CU
    gemm128<false><<<dim3(Mc / 128, Dc / 64, 3), bb, 0, stream>>>(
        q, k, v, wqb, wkb, wvb, bq, bk, bv, qh_bf, kh_bf, vt_bf,
        SCALE_Q, 1.0f, 1.0f, 1, 1, 2);
    attn_mfma<<<dim3(Sc / 128, Bc * Hc), dim3(512), 0, stream>>>(qh_bf, kh_bf, vt_bf,
                                                                 (const unsigned*)mb64, ctx);
    gemm128<true><<<dim3(Mc / 128, Dc / 64, 1), bb, 0, stream>>>(
        ctx, ctx, ctx, wob, wob, wob, bo, bo, bo, out, out, out,
        1.0f, 1.0f, 1.0f, 0, 0, 0);
}

// Round 2
// 406.234 us; speedup vs baseline: 1.6203x; 1.6203x over previous
//
#include <hip/hip_runtime.h>
#include <math.h>

// Problem constants
constexpr int Bc  = 4;
constexpr int Sc  = 2048;
constexpr int Dc  = 512;
constexpr int Hc  = 8;
constexpr int DKc = 64;
constexpr int Mc  = Bc * Sc;   // 8192 rows

constexpr float SCALE_Q = 0.180336880111120426f;   // (1/8) * log2(e): /H quirk + exp2 base

typedef __attribute__((ext_vector_type(8)))  short s16x8;   // 8 bf16 MFMA frag
typedef __attribute__((ext_vector_type(4)))  float f32x4;   // 16x16 accumulator
typedef __attribute__((ext_vector_type(16))) float f32x16;  // 32x32 accumulator

__device__ __forceinline__ unsigned short f2bf(float f) {
    __bf16 h = (__bf16)f;                 // RNE convert
    return __builtin_bit_cast(unsigned short, h);
}

__device__ __forceinline__ float fexp2(float x) {
#if __has_builtin(__builtin_amdgcn_exp2f)
    return __builtin_amdgcn_exp2f(x);
#else
    return __expf(x * 0.6931471805599453f);
#endif
}

__device__ __forceinline__ uint4 pack8(float4 a, float4 b) {
    uint4 u;
    u.x = (unsigned)f2bf(a.x) | ((unsigned)f2bf(a.y) << 16);
    u.y = (unsigned)f2bf(a.z) | ((unsigned)f2bf(a.w) << 16);
    u.z = (unsigned)f2bf(b.x) | ((unsigned)f2bf(b.y) << 16);
    u.w = (unsigned)f2bf(b.z) | ((unsigned)f2bf(b.w) << 16);
    return u;
}

// ---------------------------------------------------------------------------
// mask [B,1,S,S] int32 -> keep-bit words: bit j of word w == (mask[w*64+j]!=0)
// ---------------------------------------------------------------------------
__global__ __launch_bounds__(256)
void pack_mask(const int* __restrict__ mask, unsigned long long* __restrict__ out,
               int nwords)
{
    int gw   = (blockIdx.x * blockDim.x + threadIdx.x) >> 6;
    int lane = threadIdx.x & 63;
    int nw   = (gridDim.x * blockDim.x) >> 6;
    for (int w0 = gw * 4; w0 < nwords; w0 += nw * 4) {
        int vals[4];
#pragma unroll
        for (int c = 0; c < 4; ++c)
            vals[c] = mask[(size_t)(w0 + c) * 64 + lane];
#pragma unroll
        for (int c = 0; c < 4; ++c) {
            unsigned long long bits = __ballot(vals[c] != 0);
            if (lane == 0) out[w0 + c] = bits;
        }
    }
}

// ---------------------------------------------------------------------------
// fp32 -> bf16 elementwise, 4 tensors (blockIdx.y selects), n4 float4s each
// ---------------------------------------------------------------------------
__global__ __launch_bounds__(256)
void cvt4(const float* __restrict__ i0, const float* __restrict__ i1,
          const float* __restrict__ i2, const float* __restrict__ i3,
          unsigned short* __restrict__ o0, unsigned short* __restrict__ o1,
          unsigned short* __restrict__ o2, unsigned short* __restrict__ o3,
          int n4)
{
    const float* in; unsigned short* out;
    switch (blockIdx.y) {
        case 0: in = i0; out = o0; break;
        case 1: in = i1; out = o1; break;
        case 2: in = i2; out = o2; break;
        default: in = i3; out = o3; break;
    }
    int i = blockIdx.x * 256 + threadIdx.x;
    if (i < n4) {
        float4 v = ((const float4*)in)[i];
        ushort4 r;
        r.x = f2bf(v.x); r.y = f2bf(v.y); r.z = f2bf(v.z); r.w = f2bf(v.w);
        ((ushort4*)out)[i] = r;
    }
}

// ---------------------------------------------------------------------------
// 128x64-tile bf16-MFMA GEMM (unchanged — attn is the focus this round)
// ---------------------------------------------------------------------------
template<bool XBF>
__global__ __launch_bounds__(256, 3)
void gemm128(const void* __restrict__ x0, const void* __restrict__ x1,
             const void* __restrict__ x2,
             const unsigned short* __restrict__ w0, const unsigned short* __restrict__ w1,
             const unsigned short* __restrict__ w2,
             const float* __restrict__ b0, const float* __restrict__ b1,
             const float* __restrict__ b2,
             void* __restrict__ o0v, void* __restrict__ o1v, void* __restrict__ o2v,
             float s0, float s1, float s2, int m0, int m1, int m2)
{
    const void* Xv; const unsigned short* W; const float* bias; void* outv;
    float scale; int mode;
    switch (blockIdx.z) {
        case 0:  Xv = x0; W = w0; bias = b0; outv = o0v; scale = s0; mode = m0; break;
        case 1:  Xv = x1; W = w1; bias = b1; outv = o1v; scale = s1; mode = m1; break;
        default: Xv = x2; W = w2; bias = b2; outv = o2v; scale = s2; mode = m2; break;
    }

    __shared__ unsigned short Xs[2][128 * 64];
    __shared__ unsigned short Ws[2][64 * 64];

    const int tid = threadIdx.x;
    const int w = tid >> 6, lane = tid & 63, ln = lane & 15, qd = lane >> 4;
    const int wm = (w >> 1) * 64, wn = (w & 1) * 32;
    const int row0 = blockIdx.x * 128, col0 = blockIdx.y * 64;

    f32x4 acc[4][2];
#pragma unroll
    for (int mt = 0; mt < 4; ++mt)
#pragma unroll
        for (int nt = 0; nt < 2; ++nt) acc[mt][nt] = f32x4{0.f, 0.f, 0.f, 0.f};

    uint4 xb[4], wr[2];
    auto load = [&](int k0) {
#pragma unroll
        for (int c = 0; c < 4; ++c) {
            int u = tid + c * 256, r = u >> 3, c8 = u & 7;
            if (XBF) {
                xb[c] = *(const uint4*)((const unsigned short*)Xv +
                                        (size_t)(row0 + r) * 512 + k0 + c8 * 8);
            } else {
                const float* xp = (const float*)Xv + (size_t)(row0 + r) * 512 + k0 + c8 * 8;
                xb[c] = pack8(*(const float4*)xp, *(const float4*)(xp + 4));
            }
        }
#pragma unroll
        for (int c = 0; c < 2; ++c) {
            int u = tid + c * 256, r = u >> 3, c8 = u & 7;
            wr[c] = *(const uint4*)(W + (size_t)(col0 + r) * 512 + k0 + c8 * 8);
        }
    };
    auto store = [&](int buf) {
#pragma unroll
        for (int c = 0; c < 4; ++c) {
            int u = tid + c * 256, r = u >> 3, c8 = u & 7;
            *(uint4*)&Xs[buf][r * 64 + ((c8 ^ (r & 7)) * 8)] = xb[c];
        }
#pragma unroll
        for (int c = 0; c < 2; ++c) {
            int u = tid + c * 256, r = u >> 3, c8 = u & 7;
            *(uint4*)&Ws[buf][r * 64 + ((c8 ^ (r & 7)) * 8)] = wr[c];
        }
    };

    load(0);
    store(0);
    for (int k0 = 0; k0 < 512; k0 += 64) {
        const int buf = (k0 >> 6) & 1;
        __syncthreads();
        if (k0 + 64 < 512) load(k0 + 64);
#pragma unroll
        for (int kc = 0; kc < 2; ++kc) {
            s16x8 af[4], bfr[2];
#pragma unroll
            for (int mt = 0; mt < 4; ++mt) {
                int r = wm + mt * 16 + ln;
                af[mt] = *(const s16x8*)&Xs[buf][r * 64 + (((kc * 4 + qd) ^ (ln & 7)) * 8)];
            }
#pragma unroll
            for (int nt = 0; nt < 2; ++nt) {
                int r = wn + nt * 16 + ln;
                bfr[nt] = *(const s16x8*)&Ws[buf][r * 64 + (((kc * 4 + qd) ^ (ln & 7)) * 8)];
            }
#pragma unroll
            for (int mt = 0; mt < 4; ++mt)
#pragma unroll
                for (int nt = 0; nt < 2; ++nt)
                    acc[mt][nt] = __builtin_amdgcn_mfma_f32_16x16x32_bf16(
                        af[mt], bfr[nt], acc[mt][nt], 0, 0, 0);
        }
        if (k0 + 64 < 512) store(buf ^ 1);
    }

#pragma unroll
    for (int nt = 0; nt < 2; ++nt) {
        const int n = col0 + wn + nt * 16 + ln;
        const float bz = bias[n];
#pragma unroll
        for (int mt = 0; mt < 4; ++mt) {
            const int mbase = row0 + wm + mt * 16 + qd * 4;
            if (mode == 0) {
                float* o = (float*)outv;
#pragma unroll
                for (int r = 0; r < 4; ++r)
                    o[(size_t)(mbase + r) * 512 + n] = acc[mt][nt][r] + bz;
            } else if (mode == 1) {
                unsigned short* o = (unsigned short*)outv;
                const int h = n >> 6, dk = n & 63;
#pragma unroll
                for (int r = 0; r < 4; ++r) {
                    int m = mbase + r, b = m >> 11, s = m & 2047;
                    o[((size_t)(b * Hc + h) * Sc + s) * 64 + dk] =
                        f2bf((acc[mt][nt][r] + bz) * scale);
                }
            } else {
                unsigned short* o = (unsigned short*)outv;
                const int h = n >> 6, dk = n & 63;
                const int b = mbase >> 11, sb = mbase & 2047;
                const int ss = (sb & ~12) | ((sb & 4) << 1) | ((sb & 8) >> 1); // swap bits 2,3
                ushort4 pk;
                pk.x = f2bf((acc[mt][nt][0] + bz) * scale);
                pk.y = f2bf((acc[mt][nt][1] + bz) * scale);
                pk.z = f2bf((acc[mt][nt][2] + bz) * scale);
                pk.w = f2bf((acc[mt][nt][3] + bz) * scale);
                *(ushort4*)(o + ((size_t)(b * Hc + h) * 64 + dk) * Sc + ss) = pk;
            }
        }
    }
}

// ---------------------------------------------------------------------------
// Split-K bf16 32x32x16-MFMA flash attention, max-free softmax,
// SINGLE-Q-STREAM / HIGH-OCCUPANCY version.
//
// r9 post-mortem: launch_bounds(512,4) capped regs at 128 while the dual-tile
// wave state needs ~172 -> catastrophic scratch spill (WRITE_SIZE 8MB->942MB).
// Occupancy is REGISTER-limited, not grid-limited: at 172 regs/wave the HW max
// is 2 waves/SIMD (8 waves/CU) -- round 0 already had that. This version cuts
// per-wave state ~in half (single 32-row q-stream per wave: o=32, qf=16, sv=16,
// pu=8, pre=16, misc -> ~110 total) so 4 waves/SIMD fit a 128-reg budget.
//
// Geometry: grid (S/64, B*H) = 1024 blocks, 256 thr = 4 waves =
// 2 q-tiles (g) x 2 key-halves (kh). LDS 2buf x 2grp x 8KB = 32KB ->
// 4 blocks/CU resident = 16 waves/CU (2x round 0's TLP, independent waves).
//
// Keeps (validated r9, passed + conflicts 8.1M->1.07M):
//   K slot(r,c)  = r*8  + (c ^ (r&7))     conflict-free read+write
//   V slot(dv,c) = c*64 + (dv ^ (c<<1))   chunk-major
// Adds s_setprio(1) around MFMA clusters (T5: +4-7% on phase-split attn).
// Math proven r4-r7: p=exp2(masked s'), masked->0; PV B-frags are the lane's
// own p regs (V key axis swap23-permuted at projection); 2-way linear combine
// through a [128][36]-f32 LDS region (16B-aligned rows), once per block.
// Spill tripwire: WRITE_SIZE must be ~8192 KB (ctx only).
// ---------------------------------------------------------------------------
__global__ __launch_bounds__(256, 4)
void attn_mfma(const unsigned short* __restrict__ qh, const unsigned short* __restrict__ kh,
               const unsigned short* __restrict__ vt, const unsigned* __restrict__ mbits,
               unsigned short* __restrict__ ctx)
{
    __shared__ uint4 smem4[2][1024];   // 2 x 16384 B = 32 KB

    const int bh = blockIdx.y, b = bh >> 3, h = bh & 7;
    const int q0 = blockIdx.x * 64;
    const int tid = threadIdx.x;
    const int w = tid >> 6;
    const int g = w >> 1;            // q-tile
    const int kh_ = w & 1;           // key half
    const int lane = tid & 63, ln = lane & 31, hf = lane >> 5;
    const int qr = q0 + g * 32 + ln;

    const int st = ((tid >> 7) << 6) | (tid & 63);   // staging id within kh-group

    // Q B-frags, resident (single tile)
    s16x8 qf[4];
    {
        const unsigned short* qp = qh + ((size_t)bh * Sc + qr) * 64 + hf * 8;
#pragma unroll
        for (int kc = 0; kc < 4; ++kc)
            qf[kc] = *(const s16x8*)(qp + kc * 16);
    }

    f32x16 o0, o1;
#pragma unroll
    for (int r = 0; r < 16; ++r) { o0[r] = 0.f; o1[r] = 0.f; }
    float lr = 0.f;

    const unsigned* mr = mbits + ((size_t)b * Sc + qr) * (Sc / 32);
    const unsigned short* kbase = kh + (size_t)bh * Sc * 64;
    const unsigned short* vbase = vt + (size_t)bh * 64 * Sc;

    const int kt0 = kh_ * 1024;
    uint4 pre[4];
    auto load_tile = [&](int kt) {
#pragma unroll
        for (int c = 0; c < 2; ++c) {       // K: 32 rows x 8 chunks
            int idx = st + c * 128, r = idx >> 3, cc = idx & 7;
            pre[c] = *(const uint4*)(kbase + (size_t)(kt + r) * 64 + cc * 8);
        }
#pragma unroll
        for (int c = 2; c < 4; ++c) {       // V: 64 dv x 4 chunks (32 keys)
            int j = st + (c - 2) * 128, dv = j >> 2, cc = j & 3;
            pre[c] = *(const uint4*)(vbase + (size_t)dv * Sc + kt + cc * 8);
        }
    };
    auto store_tile = [&](int buf) {
        unsigned short* Ks = (unsigned short*)smem4[buf] + kh_ * 4096;  // 8 KB / group
        unsigned short* Vs = Ks + 2048;
#pragma unroll
        for (int c = 0; c < 2; ++c) {       // K swizzle: slot = r*8 + (cc ^ (r&7))
            int idx = st + c * 128, r = idx >> 3, cc = idx & 7;
            *(uint4*)&Ks[r * 64 + ((cc ^ (r & 7)) * 8)] = pre[c];
        }
#pragma unroll
        for (int c = 2; c < 4; ++c) {       // V swizzle: slot = cc*64 + (dv ^ (cc<<1))
            int j = st + (c - 2) * 128, dv = j >> 2, cc = j & 3;
            *(uint4*)&Vs[(cc * 64 + (dv ^ (cc << 1))) * 8] = pre[c];
        }
    };

    load_tile(kt0);
    unsigned mwn = mr[kt0 >> 5];
    store_tile(0);

    for (int i = 0; i < 32; ++i) {
        const int kt = kt0 + i * 32;
        const int buf = i & 1;
        __syncthreads();
        const unsigned mw = mwn;
        if (i < 31) {
            load_tile(kt + 32);
            mwn = mr[(kt + 32) >> 5];
        }

        const unsigned short* Ks = (const unsigned short*)smem4[buf] + kh_ * 4096;
        const unsigned short* Vs = Ks + 2048;

        // ---- S^T[key][q] = K · Q^T
        f32x16 sv;
#pragma unroll
        for (int r = 0; r < 16; ++r) sv[r] = 0.f;
        __builtin_amdgcn_s_setprio(1);
#pragma unroll
        for (int kc = 0; kc < 4; ++kc) {
            s16x8 kf = *(const s16x8*)&Ks[ln * 64 + ((((kc << 1) | hf) ^ (ln & 7)) * 8)];
            sv = __builtin_amdgcn_mfma_f32_32x32x16_bf16(kf, qf[kc], sv, 0, 0, 0);
        }
        __builtin_amdgcn_s_setprio(0);

        // ---- mask + exp2 (no max: scores bounded), pack to bf16 pairs
        float ps = 0.f;
        unsigned pu[8];
#pragma unroll
        for (int r = 0; r < 16; r += 2) {
            int key0 = (r & 3) + 8 * (r >> 2) + 4 * hf;
            int key1 = ((r + 1) & 3) + 8 * ((r + 1) >> 2) + 4 * hf;
            float a0 = ((mw >> key0) & 1u) ? sv[r]     : -1e9f;
            float a1 = ((mw >> key1) & 1u) ? sv[r + 1] : -1e9f;
            float p0 = fexp2(a0), p1 = fexp2(a1);
            ps += p0 + p1;
            pu[r >> 1] = (unsigned)f2bf(p0) | ((unsigned)f2bf(p1) << 16);
        }
        lr += ps;

        // ---- ctx^T[dv][q] += V · P^T
        __builtin_amdgcn_s_setprio(1);
#pragma unroll
        for (int kc = 0; kc < 2; ++kc) {
            uint4 ua; ua.x = pu[4*kc]; ua.y = pu[4*kc+1]; ua.z = pu[4*kc+2]; ua.w = pu[4*kc+3];
            s16x8 pf = __builtin_bit_cast(s16x8, ua);
            const int cc = (kc << 1) | hf;
            s16x8 v0  = *(const s16x8*)&Vs[(cc * 64 + (ln ^ (cc << 1))) * 8];
            s16x8 v1  = *(const s16x8*)&Vs[(cc * 64 + ((32 + ln) ^ (cc << 1))) * 8];
            o0 = __builtin_amdgcn_mfma_f32_32x32x16_bf16(v0, pf, o0, 0, 0, 0);
            o1 = __builtin_amdgcn_mfma_f32_32x32x16_bf16(v1, pf, o1, 0, 0, 0);
        }
        __builtin_amdgcn_s_setprio(0);

        if (i < 31) store_tile(buf ^ 1);
    }

    // l per-hf partial -> full
    lr += __shfl_xor(lr, 32);

    // ---- cross-half combine (linear). kh=1 -> LDS, kh=0 adds + writes.
    // Region [128][36] f32 = 18432 B (rows 144 B: 16B-aligned float4s).
    __syncthreads();
    float* cs = (float*)smem4[0];
    float* my = cs + (size_t)(g * 64 + lane) * 36;
    if (kh_ == 1) {
#pragma unroll
        for (int r = 0; r < 4; ++r) {
            *(float4*)(my + 4 * r)      = make_float4(o0[4*r], o0[4*r+1], o0[4*r+2], o0[4*r+3]);
            *(float4*)(my + 16 + 4 * r) = make_float4(o1[4*r], o1[4*r+1], o1[4*r+2], o1[4*r+3]);
        }
        my[32] = lr;
    }
    __syncthreads();
    if (kh_ == 0) {
        lr += my[32];
        const float inv = 1.f / lr;
#pragma unroll
        for (int r = 0; r < 4; ++r) {
            float4 a0 = *(const float4*)(my + 4 * r);
            float4 a1 = *(const float4*)(my + 16 + 4 * r);
            o0[4*r]   = (o0[4*r]   + a0.x) * inv; o0[4*r+1] = (o0[4*r+1] + a0.y) * inv;
            o0[4*r+2] = (o0[4*r+2] + a0.z) * inv; o0[4*r+3] = (o0[4*r+3] + a0.w) * inv;
            o1[4*r]   = (o1[4*r]   + a1.x) * inv; o1[4*r+1] = (o1[4*r+1] + a1.y) * inv;
            o1[4*r+2] = (o1[4*r+2] + a1.z) * inv; o1[4*r+3] = (o1[4*r+3] + a1.w) * inv;
        }
        // ctx bf16 [B,S,D]; dv = 8*gg + 4*hf + t (+32 for the o1 half)
        unsigned short* op = ctx + ((size_t)(b * Sc + qr)) * 512 + h * 64;
#pragma unroll
        for (int gg = 0; gg < 4; ++gg) {
            ushort4 a, c;
            a.x = f2bf(o0[gg*4+0]); a.y = f2bf(o0[gg*4+1]);
            a.z = f2bf(o0[gg*4+2]); a.w = f2bf(o0[gg*4+3]);
            c.x = f2bf(o1[gg*4+0]); c.y = f2bf(o1[gg*4+1]);
            c.z = f2bf(o1[gg*4+2]); c.w = f2bf(o1[gg*4+3]);
            *(ushort4*)(op + 8 * gg + 4 * hf)      = a;
            *(ushort4*)(op + 32 + 8 * gg + 4 * hf) = c;
        }
    }
}

// ---------------------------------------------------------------------------
extern "C" void kernel_launch(void* const* d_in, const int* in_sizes, int n_in,
                              void* d_out, int out_size, void* d_ws, size_t ws_size,
                              hipStream_t stream)
{
    (void)in_sizes; (void)n_in; (void)out_size; (void)ws_size;

    const float* q    = (const float*)d_in[0];
    const float* k    = (const float*)d_in[1];
    const float* v    = (const float*)d_in[2];
    const int*   mask = (const int*)  d_in[3];
    const float* Wq   = (const float*)d_in[4];
    const float* bq   = (const float*)d_in[5];
    const float* Wk   = (const float*)d_in[6];
    const float* bk   = (const float*)d_in[7];
    const float* Wv   = (const float*)d_in[8];
    const float* bv   = (const float*)d_in[9];
    const float* Wo   = (const float*)d_in[10];
    const float* bo   = (const float*)d_in[11];
    float* out = (float*)d_out;

    // workspace carve; TEN = 4,194,304 elems
    constexpr size_t TEN = (size_t)Bc * Hc * Sc * DKc;
    char* p = (char*)d_ws;
    unsigned short* wqb   = (unsigned short*)p;  p += (size_t)Dc * Dc * 2;  // 0.5 MB
    unsigned short* wkb   = (unsigned short*)p;  p += (size_t)Dc * Dc * 2;
    unsigned short* wvb   = (unsigned short*)p;  p += (size_t)Dc * Dc * 2;
    unsigned short* wob   = (unsigned short*)p;  p += (size_t)Dc * Dc * 2;
    unsigned short* qh_bf = (unsigned short*)p;  p += TEN * 2;              // 8 MB
    unsigned short* kh_bf = (unsigned short*)p;  p += TEN * 2;
    unsigned short* vt_bf = (unsigned short*)p;  p += TEN * 2;
    unsigned short* ctx   = (unsigned short*)p;  p += TEN * 2;
    unsigned long long* mb64 = (unsigned long long*)p;                      // 2 MB

    const int nwords = Bc * Sc * (Sc / 64);   // 262144

    dim3 bb(256);

    pack_mask<<<dim3(16384), bb, 0, stream>>>(mask, mb64, nwords);
    cvt4<<<dim3(Dc * Dc / 4 / 256, 4), bb, 0, stream>>>(Wq, Wk, Wv, Wo, wqb, wkb, wvb, wob,
                                                        Dc * Dc / 4);
    // merged Q/K/V projections: one dispatch, 1536 blocks, 3 blocks/CU
    gemm128<false><<<dim3(Mc / 128, Dc / 64, 3), bb, 0, stream>>>(
        q, k, v, wqb, wkb, wvb, bq, bk, bv, qh_bf, kh_bf, vt_bf,
        SCALE_Q, 1.0f, 1.0f, 1, 1, 2);
    attn_mfma<<<dim3(Sc / 64, Bc * Hc), bb, 0, stream>>>(qh_bf, kh_bf, vt_bf,
                                                         (const unsigned*)mb64, ctx);
    gemm128<true><<<dim3(Mc / 128, Dc / 64, 1), bb, 0, stream>>>(
        ctx, ctx, ctx, wob, wob, wob, bo, bo, bo, out, out, out,
        1.0f, 1.0f, 1.0f, 0, 0, 0);
}

// Round 3
// 323.613 us; speedup vs baseline: 2.0340x; 1.2553x over previous
//
#include <hip/hip_runtime.h>
#include <math.h>

// Problem constants
constexpr int Bc  = 4;
constexpr int Sc  = 2048;
constexpr int Dc  = 512;
constexpr int Hc  = 8;
constexpr int DKc = 64;
constexpr int Mc  = Bc * Sc;   // 8192 rows

constexpr float SCALE_Q = 0.180336880111120426f;   // (1/8) * log2(e): /H quirk + exp2 base

typedef __attribute__((ext_vector_type(8)))  short s16x8;   // 8 bf16 MFMA frag
typedef __attribute__((ext_vector_type(4)))  float f32x4;   // 16x16 accumulator
typedef __attribute__((ext_vector_type(16))) float f32x16;  // 32x32 accumulator

__device__ __forceinline__ unsigned short f2bf(float f) {
    __bf16 h = (__bf16)f;                 // RNE convert
    return __builtin_bit_cast(unsigned short, h);
}

__device__ __forceinline__ float fexp2(float x) {
#if __has_builtin(__builtin_amdgcn_exp2f)
    return __builtin_amdgcn_exp2f(x);
#else
    return __expf(x * 0.6931471805599453f);
#endif
}

__device__ __forceinline__ uint4 pack8(float4 a, float4 b) {
    uint4 u;
    u.x = (unsigned)f2bf(a.x) | ((unsigned)f2bf(a.y) << 16);
    u.y = (unsigned)f2bf(a.z) | ((unsigned)f2bf(a.w) << 16);
    u.z = (unsigned)f2bf(b.x) | ((unsigned)f2bf(b.y) << 16);
    u.w = (unsigned)f2bf(b.z) | ((unsigned)f2bf(b.w) << 16);
    return u;
}

// ---------------------------------------------------------------------------
// mask [B,1,S,S] int32 -> keep-bit words: bit j of word w == (mask[w*64+j]!=0)
// ---------------------------------------------------------------------------
__global__ __launch_bounds__(256)
void pack_mask(const int* __restrict__ mask, unsigned long long* __restrict__ out,
               int nwords)
{
    int gw   = (blockIdx.x * blockDim.x + threadIdx.x) >> 6;
    int lane = threadIdx.x & 63;
    int nw   = (gridDim.x * blockDim.x) >> 6;
    for (int w0 = gw * 4; w0 < nwords; w0 += nw * 4) {
        int vals[4];
#pragma unroll
        for (int c = 0; c < 4; ++c)
            vals[c] = mask[(size_t)(w0 + c) * 64 + lane];
#pragma unroll
        for (int c = 0; c < 4; ++c) {
            unsigned long long bits = __ballot(vals[c] != 0);
            if (lane == 0) out[w0 + c] = bits;
        }
    }
}

// ---------------------------------------------------------------------------
// fp32 -> bf16 elementwise, 4 tensors (blockIdx.y selects), n4 float4s each
// ---------------------------------------------------------------------------
__global__ __launch_bounds__(256)
void cvt4(const float* __restrict__ i0, const float* __restrict__ i1,
          const float* __restrict__ i2, const float* __restrict__ i3,
          unsigned short* __restrict__ o0, unsigned short* __restrict__ o1,
          unsigned short* __restrict__ o2, unsigned short* __restrict__ o3,
          int n4)
{
    const float* in; unsigned short* out;
    switch (blockIdx.y) {
        case 0: in = i0; out = o0; break;
        case 1: in = i1; out = o1; break;
        case 2: in = i2; out = o2; break;
        default: in = i3; out = o3; break;
    }
    int i = blockIdx.x * 256 + threadIdx.x;
    if (i < n4) {
        float4 v = ((const float4*)in)[i];
        ushort4 r;
        r.x = f2bf(v.x); r.y = f2bf(v.y); r.z = f2bf(v.z); r.w = f2bf(v.w);
        ((ushort4*)out)[i] = r;
    }
}

// ---------------------------------------------------------------------------
// 128x64-tile bf16-MFMA GEMM (unchanged — attn is the focus this round)
// ---------------------------------------------------------------------------
template<bool XBF>
__global__ __launch_bounds__(256, 3)
void gemm128(const void* __restrict__ x0, const void* __restrict__ x1,
             const void* __restrict__ x2,
             const unsigned short* __restrict__ w0, const unsigned short* __restrict__ w1,
             const unsigned short* __restrict__ w2,
             const float* __restrict__ b0, const float* __restrict__ b1,
             const float* __restrict__ b2,
             void* __restrict__ o0v, void* __restrict__ o1v, void* __restrict__ o2v,
             float s0, float s1, float s2, int m0, int m1, int m2)
{
    const void* Xv; const unsigned short* W; const float* bias; void* outv;
    float scale; int mode;
    switch (blockIdx.z) {
        case 0:  Xv = x0; W = w0; bias = b0; outv = o0v; scale = s0; mode = m0; break;
        case 1:  Xv = x1; W = w1; bias = b1; outv = o1v; scale = s1; mode = m1; break;
        default: Xv = x2; W = w2; bias = b2; outv = o2v; scale = s2; mode = m2; break;
    }

    __shared__ unsigned short Xs[2][128 * 64];
    __shared__ unsigned short Ws[2][64 * 64];

    const int tid = threadIdx.x;
    const int w = tid >> 6, lane = tid & 63, ln = lane & 15, qd = lane >> 4;
    const int wm = (w >> 1) * 64, wn = (w & 1) * 32;
    const int row0 = blockIdx.x * 128, col0 = blockIdx.y * 64;

    f32x4 acc[4][2];
#pragma unroll
    for (int mt = 0; mt < 4; ++mt)
#pragma unroll
        for (int nt = 0; nt < 2; ++nt) acc[mt][nt] = f32x4{0.f, 0.f, 0.f, 0.f};

    uint4 xb[4], wr[2];
    auto load = [&](int k0) {
#pragma unroll
        for (int c = 0; c < 4; ++c) {
            int u = tid + c * 256, r = u >> 3, c8 = u & 7;
            if (XBF) {
                xb[c] = *(const uint4*)((const unsigned short*)Xv +
                                        (size_t)(row0 + r) * 512 + k0 + c8 * 8);
            } else {
                const float* xp = (const float*)Xv + (size_t)(row0 + r) * 512 + k0 + c8 * 8;
                xb[c] = pack8(*(const float4*)xp, *(const float4*)(xp + 4));
            }
        }
#pragma unroll
        for (int c = 0; c < 2; ++c) {
            int u = tid + c * 256, r = u >> 3, c8 = u & 7;
            wr[c] = *(const uint4*)(W + (size_t)(col0 + r) * 512 + k0 + c8 * 8);
        }
    };
    auto store = [&](int buf) {
#pragma unroll
        for (int c = 0; c < 4; ++c) {
            int u = tid + c * 256, r = u >> 3, c8 = u & 7;
            *(uint4*)&Xs[buf][r * 64 + ((c8 ^ (r & 7)) * 8)] = xb[c];
        }
#pragma unroll
        for (int c = 0; c < 2; ++c) {
            int u = tid + c * 256, r = u >> 3, c8 = u & 7;
            *(uint4*)&Ws[buf][r * 64 + ((c8 ^ (r & 7)) * 8)] = wr[c];
        }
    };

    load(0);
    store(0);
    for (int k0 = 0; k0 < 512; k0 += 64) {
        const int buf = (k0 >> 6) & 1;
        __syncthreads();
        if (k0 + 64 < 512) load(k0 + 64);
#pragma unroll
        for (int kc = 0; kc < 2; ++kc) {
            s16x8 af[4], bfr[2];
#pragma unroll
            for (int mt = 0; mt < 4; ++mt) {
                int r = wm + mt * 16 + ln;
                af[mt] = *(const s16x8*)&Xs[buf][r * 64 + (((kc * 4 + qd) ^ (ln & 7)) * 8)];
            }
#pragma unroll
            for (int nt = 0; nt < 2; ++nt) {
                int r = wn + nt * 16 + ln;
                bfr[nt] = *(const s16x8*)&Ws[buf][r * 64 + (((kc * 4 + qd) ^ (ln & 7)) * 8)];
            }
#pragma unroll
            for (int mt = 0; mt < 4; ++mt)
#pragma unroll
                for (int nt = 0; nt < 2; ++nt)
                    acc[mt][nt] = __builtin_amdgcn_mfma_f32_16x16x32_bf16(
                        af[mt], bfr[nt], acc[mt][nt], 0, 0, 0);
        }
        if (k0 + 64 < 512) store(buf ^ 1);
    }

#pragma unroll
    for (int nt = 0; nt < 2; ++nt) {
        const int n = col0 + wn + nt * 16 + ln;
        const float bz = bias[n];
#pragma unroll
        for (int mt = 0; mt < 4; ++mt) {
            const int mbase = row0 + wm + mt * 16 + qd * 4;
            if (mode == 0) {
                float* o = (float*)outv;
#pragma unroll
                for (int r = 0; r < 4; ++r)
                    o[(size_t)(mbase + r) * 512 + n] = acc[mt][nt][r] + bz;
            } else if (mode == 1) {
                unsigned short* o = (unsigned short*)outv;
                const int h = n >> 6, dk = n & 63;
#pragma unroll
                for (int r = 0; r < 4; ++r) {
                    int m = mbase + r, b = m >> 11, s = m & 2047;
                    o[((size_t)(b * Hc + h) * Sc + s) * 64 + dk] =
                        f2bf((acc[mt][nt][r] + bz) * scale);
                }
            } else {
                unsigned short* o = (unsigned short*)outv;
                const int h = n >> 6, dk = n & 63;
                const int b = mbase >> 11, sb = mbase & 2047;
                const int ss = (sb & ~12) | ((sb & 4) << 1) | ((sb & 8) >> 1); // swap bits 2,3
                ushort4 pk;
                pk.x = f2bf((acc[mt][nt][0] + bz) * scale);
                pk.y = f2bf((acc[mt][nt][1] + bz) * scale);
                pk.z = f2bf((acc[mt][nt][2] + bz) * scale);
                pk.w = f2bf((acc[mt][nt][3] + bz) * scale);
                *(ushort4*)(o + ((size_t)(b * Hc + h) * 64 + dk) * Sc + ss) = pk;
            }
        }
    }
}

// ---------------------------------------------------------------------------
// Split-K bf16 32x32x16-MFMA flash attention, max-free softmax,
// single-q-stream, DMA-STAGED (global_load_lds) version.
//
// r10 post-mortem: launch_bounds(.,4) made the compiler split the 128-reg
// budget 64 arch + 64 acc; arch demand was ~90 (16 of it the `pre` staging
// regs) -> ~16 regs spilled per iter -> WRITE_SIZE 470MB of scratch. Fix:
// remove arch pressure instead of capping. global_load_lds (width 16) DMAs
// global->LDS directly: deletes pre[4] + all ds_writes + staging VALU.
// DMA writes LDS LINEARLY (wave base + lane*16), so per rule #21 the global
// SOURCE is inverse-swizzled and the LDS layout stays byte-identical to r10:
//   K linear slot s holds chunk cc=(s&7)^(r&7) of row r=s>>3
//   V linear slot s holds dv=(s&63)^(cc<<1),  cc=s>>6
// Read-side swizzled formulas unchanged (proven r9/r10).
// launch_bounds(256,3): cap 170 -> spill impossible (~110 demand); natural
// allocation ~55 arch + 48 acc <= 128 total should still give 4 waves/SIMD.
// Combine region: stride 36 floats was an 8-way bank conflict (the remaining
// 2.1M cycles) -> stride 48 + XOR slot swizzle (q ^ (row&7)) = conflict-free.
// Spill tripwire: WRITE_SIZE must be ~8 MB (ctx only).
// ---------------------------------------------------------------------------
__global__ __launch_bounds__(256, 3)
void attn_mfma(const unsigned short* __restrict__ qh, const unsigned short* __restrict__ kh,
               const unsigned short* __restrict__ vt, const unsigned* __restrict__ mbits,
               unsigned short* __restrict__ ctx)
{
    __shared__ uint4 smem4[2][1024];   // 2 x 16384 B = 32 KB

    const int bh = blockIdx.y, b = bh >> 3, h = bh & 7;
    const int q0 = blockIdx.x * 64;
    const int tid = threadIdx.x;
    const int w = tid >> 6;
    const int g = w >> 1;            // q-tile
    const int kh_ = w & 1;           // key half
    const int lane = tid & 63, ln = lane & 31, hf = lane >> 5;
    const int wv = tid >> 7;         // wave index within kh-group (0/1)
    const int qr = q0 + g * 32 + ln;

    // Q B-frags, resident (single tile)
    s16x8 qf[4];
    {
        const unsigned short* qp = qh + ((size_t)bh * Sc + qr) * 64 + hf * 8;
#pragma unroll
        for (int kc = 0; kc < 4; ++kc)
            qf[kc] = *(const s16x8*)(qp + kc * 16);
    }

    f32x16 o0, o1;
#pragma unroll
    for (int r = 0; r < 16; ++r) { o0[r] = 0.f; o1[r] = 0.f; }
    float lr = 0.f;

    const unsigned* mr = mbits + ((size_t)b * Sc + qr) * (Sc / 32);
    const unsigned short* kbase = kh + (size_t)bh * Sc * 64;
    const unsigned short* vbase = vt + (size_t)bh * 64 * Sc;

    const int kt0 = kh_ * 1024;

    // DMA stage: linear LDS dest (wave base + lane*16), inverse-swizzled
    // global source. Per kh-group: 8 KB = K 4KB (4 segs) + V 4KB (4 segs);
    // each of the group's 2 waves DMAs 2 K-segs + 2 V-segs of 1 KB.
    auto stage_tile = [&](int buf, int kt) {
        char* gb = (char*)smem4[buf] + kh_ * 8192;
#pragma unroll
        for (int c = 0; c < 2; ++c) {
            const int seg = wv * 2 + c;                  // wave-uniform
            const int s   = seg * 64 + lane;             // linear 16B slot
            const int r   = s >> 3, cc = (s & 7) ^ (r & 7);
            const unsigned short* gs = kbase + (size_t)(kt + r) * 64 + cc * 8;
            __builtin_amdgcn_global_load_lds(
                (const __attribute__((address_space(1))) unsigned int*)gs,
                (__attribute__((address_space(3))) unsigned int*)(gb + seg * 1024),
                16, 0, 0);
        }
        char* vb = gb + 4096;
#pragma unroll
        for (int c = 0; c < 2; ++c) {
            const int seg = wv * 2 + c;                  // = cc (chunk index)
            const int dv  = lane ^ (seg << 1);
            const unsigned short* gs = vbase + (size_t)dv * Sc + kt + seg * 8;
            __builtin_amdgcn_global_load_lds(
                (const __attribute__((address_space(1))) unsigned int*)gs,
                (__attribute__((address_space(3))) unsigned int*)(vb + seg * 1024),
                16, 0, 0);
        }
    };

    stage_tile(0, kt0);
    unsigned mwn = mr[kt0 >> 5];

    for (int i = 0; i < 32; ++i) {
        const int kt = kt0 + i * 32;
        const int buf = i & 1;
        __syncthreads();          // drains this wave's DMA (vmcnt) + orders buf reuse
        const unsigned mw = mwn;
        if (i < 31) {
            stage_tile(buf ^ 1, kt + 32);
            mwn = mr[(kt + 32) >> 5];
        }

        const unsigned short* Ks = (const unsigned short*)smem4[buf] + kh_ * 4096;
        const unsigned short* Vs = Ks + 2048;

        // ---- S^T[key][q] = K · Q^T
        f32x16 sv;
#pragma unroll
        for (int r = 0; r < 16; ++r) sv[r] = 0.f;
        __builtin_amdgcn_s_setprio(1);
#pragma unroll
        for (int kc = 0; kc < 4; ++kc) {
            s16x8 kf = *(const s16x8*)&Ks[ln * 64 + ((((kc << 1) | hf) ^ (ln & 7)) * 8)];
            sv = __builtin_amdgcn_mfma_f32_32x32x16_bf16(kf, qf[kc], sv, 0, 0, 0);
        }
        __builtin_amdgcn_s_setprio(0);

        // ---- mask + exp2 (no max: scores bounded), pack to bf16 pairs
        float ps = 0.f;
        unsigned pu[8];
#pragma unroll
        for (int r = 0; r < 16; r += 2) {
            int key0 = (r & 3) + 8 * (r >> 2) + 4 * hf;
            int key1 = ((r + 1) & 3) + 8 * ((r + 1) >> 2) + 4 * hf;
            float a0 = ((mw >> key0) & 1u) ? sv[r]     : -1e9f;
            float a1 = ((mw >> key1) & 1u) ? sv[r + 1] : -1e9f;
            float p0 = fexp2(a0), p1 = fexp2(a1);
            ps += p0 + p1;
            pu[r >> 1] = (unsigned)f2bf(p0) | ((unsigned)f2bf(p1) << 16);
        }
        lr += ps;

        // ---- ctx^T[dv][q] += V · P^T
        __builtin_amdgcn_s_setprio(1);
#pragma unroll
        for (int kc = 0; kc < 2; ++kc) {
            uint4 ua; ua.x = pu[4*kc]; ua.y = pu[4*kc+1]; ua.z = pu[4*kc+2]; ua.w = pu[4*kc+3];
            s16x8 pf = __builtin_bit_cast(s16x8, ua);
            const int cc = (kc << 1) | hf;
            s16x8 v0  = *(const s16x8*)&Vs[(cc * 64 + (ln ^ (cc << 1))) * 8];
            s16x8 v1  = *(const s16x8*)&Vs[(cc * 64 + ((32 + ln) ^ (cc << 1))) * 8];
            o0 = __builtin_amdgcn_mfma_f32_32x32x16_bf16(v0, pf, o0, 0, 0, 0);
            o1 = __builtin_amdgcn_mfma_f32_32x32x16_bf16(v1, pf, o1, 0, 0, 0);
        }
        __builtin_amdgcn_s_setprio(0);
    }

    // l per-hf partial -> full
    lr += __shfl_xor(lr, 32);

    // ---- cross-half combine (linear). kh=1 -> LDS, kh=0 adds + writes.
    // Region [128][48] f32 = 24576 B; float4 slot q stored at (q ^ (row&7)):
    // 8 lanes cover all 32 banks -> conflict-free (was 8-way at stride 36).
    __syncthreads();
    float* cs = (float*)smem4[0];
    const int row = g * 64 + lane;
    float* my = cs + (size_t)row * 48;
    const int sw = lane & 7;
    if (kh_ == 1) {
#pragma unroll
        for (int r = 0; r < 4; ++r) {
            *(float4*)(my + ((r ^ sw) * 4))       = make_float4(o0[4*r], o0[4*r+1], o0[4*r+2], o0[4*r+3]);
            *(float4*)(my + (((r + 4) ^ sw) * 4)) = make_float4(o1[4*r], o1[4*r+1], o1[4*r+2], o1[4*r+3]);
        }
        my[32] = lr;
    }
    __syncthreads();
    if (kh_ == 0) {
        lr += my[32];
        const float inv = 1.f / lr;
#pragma unroll
        for (int r = 0; r < 4; ++r) {
            float4 a0 = *(const float4*)(my + ((r ^ sw) * 4));
            float4 a1 = *(const float4*)(my + (((r + 4) ^ sw) * 4));
            o0[4*r]   = (o0[4*r]   + a0.x) * inv; o0[4*r+1] = (o0[4*r+1] + a0.y) * inv;
            o0[4*r+2] = (o0[4*r+2] + a0.z) * inv; o0[4*r+3] = (o0[4*r+3] + a0.w) * inv;
            o1[4*r]   = (o1[4*r]   + a1.x) * inv; o1[4*r+1] = (o1[4*r+1] + a1.y) * inv;
            o1[4*r+2] = (o1[4*r+2] + a1.z) * inv; o1[4*r+3] = (o1[4*r+3] + a1.w) * inv;
        }
        // ctx bf16 [B,S,D]; dv = 8*gg + 4*hf + t (+32 for the o1 half)
        unsigned short* op = ctx + ((size_t)(b * Sc + qr)) * 512 + h * 64;
#pragma unroll
        for (int gg = 0; gg < 4; ++gg) {
            ushort4 a, c;
            a.x = f2bf(o0[gg*4+0]); a.y = f2bf(o0[gg*4+1]);
            a.z = f2bf(o0[gg*4+2]); a.w = f2bf(o0[gg*4+3]);
            c.x = f2bf(o1[gg*4+0]); c.y = f2bf(o1[gg*4+1]);
            c.z = f2bf(o1[gg*4+2]); c.w = f2bf(o1[gg*4+3]);
            *(ushort4*)(op + 8 * gg + 4 * hf)      = a;
            *(ushort4*)(op + 32 + 8 * gg + 4 * hf) = c;
        }
    }
}

// ---------------------------------------------------------------------------
extern "C" void kernel_launch(void* const* d_in, const int* in_sizes, int n_in,
                              void* d_out, int out_size, void* d_ws, size_t ws_size,
                              hipStream_t stream)
{
    (void)in_sizes; (void)n_in; (void)out_size; (void)ws_size;

    const float* q    = (const float*)d_in[0];
    const float* k    = (const float*)d_in[1];
    const float* v    = (const float*)d_in[2];
    const int*   mask = (const int*)  d_in[3];
    const float* Wq   = (const float*)d_in[4];
    const float* bq   = (const float*)d_in[5];
    const float* Wk   = (const float*)d_in[6];
    const float* bk   = (const float*)d_in[7];
    const float* Wv   = (const float*)d_in[8];
    const float* bv   = (const float*)d_in[9];
    const float* Wo   = (const float*)d_in[10];
    const float* bo   = (const float*)d_in[11];
    float* out = (float*)d_out;

    // workspace carve; TEN = 4,194,304 elems
    constexpr size_t TEN = (size_t)Bc * Hc * Sc * DKc;
    char* p = (char*)d_ws;
    unsigned short* wqb   = (unsigned short*)p;  p += (size_t)Dc * Dc * 2;  // 0.5 MB
    unsigned short* wkb   = (unsigned short*)p;  p += (size_t)Dc * Dc * 2;
    unsigned short* wvb   = (unsigned short*)p;  p += (size_t)Dc * Dc * 2;
    unsigned short* wob   = (unsigned short*)p;  p += (size_t)Dc * Dc * 2;
    unsigned short* qh_bf = (unsigned short*)p;  p += TEN * 2;              // 8 MB
    unsigned short* kh_bf = (unsigned short*)p;  p += TEN * 2;
    unsigned short* vt_bf = (unsigned short*)p;  p += TEN * 2;
    unsigned short* ctx   = (unsigned short*)p;  p += TEN * 2;
    unsigned long long* mb64 = (unsigned long long*)p;                      // 2 MB

    const int nwords = Bc * Sc * (Sc / 64);   // 262144

    dim3 bb(256);

    pack_mask<<<dim3(16384), bb, 0, stream>>>(mask, mb64, nwords);
    cvt4<<<dim3(Dc * Dc / 4 / 256, 4), bb, 0, stream>>>(Wq, Wk, Wv, Wo, wqb, wkb, wvb, wob,
                                                        Dc * Dc / 4);
    // merged Q/K/V projections: one dispatch, 1536 blocks, 3 blocks/CU
    gemm128<false><<<dim3(Mc / 128, Dc / 64, 3), bb, 0, stream>>>(
        q, k, v, wqb, wkb, wvb, bq, bk, bv, qh_bf, kh_bf, vt_bf,
        SCALE_Q, 1.0f, 1.0f, 1, 1, 2);
    attn_mfma<<<dim3(Sc / 64, Bc * Hc), bb, 0, stream>>>(qh_bf, kh_bf, vt_bf,
                                                         (const unsigned*)mb64, ctx);
    gemm128<true><<<dim3(Mc / 128, Dc / 64, 1), bb, 0, stream>>>(
        ctx, ctx, ctx, wob, wob, wob, bo, bo, bo, out, out, out,
        1.0f, 1.0f, 1.0f, 0, 0, 0);
}

// Round 4
// 268.125 us; speedup vs baseline: 2.4549x; 1.2070x over previous
//
#include <hip/hip_runtime.h>
#include <math.h>

// Problem constants
constexpr int Bc  = 4;
constexpr int Sc  = 2048;
constexpr int Dc  = 512;
constexpr int Hc  = 8;
constexpr int DKc = 64;
constexpr int Mc  = Bc * Sc;   // 8192 rows

constexpr float SCALE_Q = 0.180336880111120426f;   // (1/8) * log2(e): /H quirk + exp2 base

typedef __attribute__((ext_vector_type(8)))  short s16x8;   // 8 bf16 MFMA frag
typedef __attribute__((ext_vector_type(4)))  float f32x4;   // 16x16 accumulator
typedef __attribute__((ext_vector_type(16))) float f32x16;  // 32x32 accumulator

__device__ __forceinline__ unsigned short f2bf(float f) {
    __bf16 h = (__bf16)f;                 // RNE convert
    return __builtin_bit_cast(unsigned short, h);
}

__device__ __forceinline__ float fexp2(float x) {
#if __has_builtin(__builtin_amdgcn_exp2f)
    return __builtin_amdgcn_exp2f(x);
#else
    return __expf(x * 0.6931471805599453f);
#endif
}

// ---------------------------------------------------------------------------
// mask [B,1,S,S] int32 -> keep-bit words: bit j of word w == (mask[w*64+j]!=0)
// ---------------------------------------------------------------------------
__global__ __launch_bounds__(256)
void pack_mask(const int* __restrict__ mask, unsigned long long* __restrict__ out,
               int nwords)
{
    int gw   = (blockIdx.x * blockDim.x + threadIdx.x) >> 6;
    int lane = threadIdx.x & 63;
    int nw   = (gridDim.x * blockDim.x) >> 6;
    for (int w0 = gw * 4; w0 < nwords; w0 += nw * 4) {
        int vals[4];
#pragma unroll
        for (int c = 0; c < 4; ++c)
            vals[c] = mask[(size_t)(w0 + c) * 64 + lane];
#pragma unroll
        for (int c = 0; c < 4; ++c) {
            unsigned long long bits = __ballot(vals[c] != 0);
            if (lane == 0) out[w0 + c] = bits;
        }
    }
}

// ---------------------------------------------------------------------------
// fp32 -> bf16 elementwise, up to 4 tensors (blockIdx.y selects), n4 float4s
// ---------------------------------------------------------------------------
__global__ __launch_bounds__(256)
void cvt4(const float* __restrict__ i0, const float* __restrict__ i1,
          const float* __restrict__ i2, const float* __restrict__ i3,
          unsigned short* __restrict__ o0, unsigned short* __restrict__ o1,
          unsigned short* __restrict__ o2, unsigned short* __restrict__ o3,
          int n4)
{
    const float* in; unsigned short* out;
    switch (blockIdx.y) {
        case 0: in = i0; out = o0; break;
        case 1: in = i1; out = o1; break;
        case 2: in = i2; out = o2; break;
        default: in = i3; out = o3; break;
    }
    int i = blockIdx.x * 256 + threadIdx.x;
    if (i < n4) {
        float4 v = ((const float4*)in)[i];
        ushort4 r;
        r.x = f2bf(v.x); r.y = f2bf(v.y); r.z = f2bf(v.z); r.w = f2bf(v.w);
        ((ushort4*)out)[i] = r;
    }
}

// ---------------------------------------------------------------------------
// 128x64-tile bf16-MFMA GEMM, DMA-STAGED (global_load_lds width 16).
//
// r11 post-mortem (QKV dispatch): 79us, MfmaUtil 6%, VALU 9%, HBM 18%,
// Occ 29% -- latency-bound. Old path per iter: 10 fp32 loads -> vmcnt(0)
// -> 48 pack-VALU -> 6 ds_writes -> barrier; HBM latency sat on the
// critical path every one of 8 K-iters. This version applies the attn r3
// recipe: inputs pre-converted to bf16, staging via global_load_lds with
// INVERSE-SWIZZLED global sources producing byte-identical LDS to the old
// swizzled store (read side unchanged, proven r7-r11):
//   LDS 16B slot s of a tile row r=s>>3 holds chunk cc=(s&7)^(r&7).
// Deletes xb/wr regs, ds_writes, and all cvt VALU from the loop.
// ---------------------------------------------------------------------------
__global__ __launch_bounds__(256, 3)
void gemm128(const unsigned short* __restrict__ x0, const unsigned short* __restrict__ x1,
             const unsigned short* __restrict__ x2,
             const unsigned short* __restrict__ w0, const unsigned short* __restrict__ w1,
             const unsigned short* __restrict__ w2,
             const float* __restrict__ b0, const float* __restrict__ b1,
             const float* __restrict__ b2,
             void* __restrict__ o0v, void* __restrict__ o1v, void* __restrict__ o2v,
             float s0, float s1, float s2, int m0, int m1, int m2)
{
    const unsigned short* X; const unsigned short* W; const float* bias; void* outv;
    float scale; int mode;
    switch (blockIdx.z) {
        case 0:  X = x0; W = w0; bias = b0; outv = o0v; scale = s0; mode = m0; break;
        case 1:  X = x1; W = w1; bias = b1; outv = o1v; scale = s1; mode = m1; break;
        default: X = x2; W = w2; bias = b2; outv = o2v; scale = s2; mode = m2; break;
    }

    __shared__ unsigned short Xs[2][128 * 64];
    __shared__ unsigned short Ws[2][64 * 64];

    const int tid = threadIdx.x;
    const int w = tid >> 6, lane = tid & 63, ln = lane & 15, qd = lane >> 4;
    const int wm = (w >> 1) * 64, wn = (w & 1) * 32;
    const int row0 = blockIdx.x * 128, col0 = blockIdx.y * 64;

    f32x4 acc[4][2];
#pragma unroll
    for (int mt = 0; mt < 4; ++mt)
#pragma unroll
        for (int nt = 0; nt < 2; ++nt) acc[mt][nt] = f32x4{0.f, 0.f, 0.f, 0.f};

    // DMA stage: linear LDS dest (wave-uniform base + lane*16), source
    // inverse-swizzled so LDS bytes match the old XOR-swizzled layout.
    auto stage = [&](int buf, int k0) {
#pragma unroll
        for (int c = 0; c < 4; ++c) {              // X tile: 1024 slots
            const int s = c * 256 + w * 64 + lane;
            const int r = s >> 3, cc = (s & 7) ^ (r & 7);
            const unsigned short* gs = X + (size_t)(row0 + r) * 512 + k0 + cc * 8;
            __builtin_amdgcn_global_load_lds(
                (const __attribute__((address_space(1))) unsigned int*)gs,
                (__attribute__((address_space(3))) unsigned int*)
                    ((char*)&Xs[buf][0] + (c * 256 + w * 64) * 16),
                16, 0, 0);
        }
#pragma unroll
        for (int c = 0; c < 2; ++c) {              // W tile: 512 slots
            const int s = c * 256 + w * 64 + lane;
            const int r = s >> 3, cc = (s & 7) ^ (r & 7);
            const unsigned short* gs = W + (size_t)(col0 + r) * 512 + k0 + cc * 8;
            __builtin_amdgcn_global_load_lds(
                (const __attribute__((address_space(1))) unsigned int*)gs,
                (__attribute__((address_space(3))) unsigned int*)
                    ((char*)&Ws[buf][0] + (c * 256 + w * 64) * 16),
                16, 0, 0);
        }
    };

    stage(0, 0);
    for (int k0 = 0; k0 < 512; k0 += 64) {
        const int buf = (k0 >> 6) & 1;
        __syncthreads();                 // drains prev DMA (vmcnt) + buf reuse
        if (k0 + 64 < 512) stage(buf ^ 1, k0 + 64);
#pragma unroll
        for (int kc = 0; kc < 2; ++kc) {
            s16x8 af[4], bfr[2];
#pragma unroll
            for (int mt = 0; mt < 4; ++mt) {
                int r = wm + mt * 16 + ln;
                af[mt] = *(const s16x8*)&Xs[buf][r * 64 + (((kc * 4 + qd) ^ (ln & 7)) * 8)];
            }
#pragma unroll
            for (int nt = 0; nt < 2; ++nt) {
                int r = wn + nt * 16 + ln;
                bfr[nt] = *(const s16x8*)&Ws[buf][r * 64 + (((kc * 4 + qd) ^ (ln & 7)) * 8)];
            }
#pragma unroll
            for (int mt = 0; mt < 4; ++mt)
#pragma unroll
                for (int nt = 0; nt < 2; ++nt)
                    acc[mt][nt] = __builtin_amdgcn_mfma_f32_16x16x32_bf16(
                        af[mt], bfr[nt], acc[mt][nt], 0, 0, 0);
        }
    }

#pragma unroll
    for (int nt = 0; nt < 2; ++nt) {
        const int n = col0 + wn + nt * 16 + ln;
        const float bz = bias[n];
#pragma unroll
        for (int mt = 0; mt < 4; ++mt) {
            const int mbase = row0 + wm + mt * 16 + qd * 4;
            if (mode == 0) {
                float* o = (float*)outv;
#pragma unroll
                for (int r = 0; r < 4; ++r)
                    o[(size_t)(mbase + r) * 512 + n] = acc[mt][nt][r] + bz;
            } else if (mode == 1) {
                unsigned short* o = (unsigned short*)outv;
                const int h = n >> 6, dk = n & 63;
#pragma unroll
                for (int r = 0; r < 4; ++r) {
                    int m = mbase + r, b = m >> 11, s = m & 2047;
                    o[((size_t)(b * Hc + h) * Sc + s) * 64 + dk] =
                        f2bf((acc[mt][nt][r] + bz) * scale);
                }
            } else {
                unsigned short* o = (unsigned short*)outv;
                const int h = n >> 6, dk = n & 63;
                const int b = mbase >> 11, sb = mbase & 2047;
                const int ss = (sb & ~12) | ((sb & 4) << 1) | ((sb & 8) >> 1); // swap bits 2,3
                ushort4 pk;
                pk.x = f2bf((acc[mt][nt][0] + bz) * scale);
                pk.y = f2bf((acc[mt][nt][1] + bz) * scale);
                pk.z = f2bf((acc[mt][nt][2] + bz) * scale);
                pk.w = f2bf((acc[mt][nt][3] + bz) * scale);
                *(ushort4*)(o + ((size_t)(b * Hc + h) * 64 + dk) * Sc + ss) = pk;
            }
        }
    }
}

// ---------------------------------------------------------------------------
// Split-K bf16 32x32x16-MFMA flash attention, max-free softmax,
// single-q-stream, DMA-STAGED (global_load_lds) version. (unchanged r3 —
// it dropped attn out of the top-5; counters pending)
// ---------------------------------------------------------------------------
__global__ __launch_bounds__(256, 3)
void attn_mfma(const unsigned short* __restrict__ qh, const unsigned short* __restrict__ kh,
               const unsigned short* __restrict__ vt, const unsigned* __restrict__ mbits,
               unsigned short* __restrict__ ctx)
{
    __shared__ uint4 smem4[2][1024];   // 2 x 16384 B = 32 KB

    const int bh = blockIdx.y, b = bh >> 3, h = bh & 7;
    const int q0 = blockIdx.x * 64;
    const int tid = threadIdx.x;
    const int w = tid >> 6;
    const int g = w >> 1;            // q-tile
    const int kh_ = w & 1;           // key half
    const int lane = tid & 63, ln = lane & 31, hf = lane >> 5;
    const int wv = tid >> 7;         // wave index within kh-group (0/1)
    const int qr = q0 + g * 32 + ln;

    // Q B-frags, resident (single tile)
    s16x8 qf[4];
    {
        const unsigned short* qp = qh + ((size_t)bh * Sc + qr) * 64 + hf * 8;
#pragma unroll
        for (int kc = 0; kc < 4; ++kc)
            qf[kc] = *(const s16x8*)(qp + kc * 16);
    }

    f32x16 o0, o1;
#pragma unroll
    for (int r = 0; r < 16; ++r) { o0[r] = 0.f; o1[r] = 0.f; }
    float lr = 0.f;

    const unsigned* mr = mbits + ((size_t)b * Sc + qr) * (Sc / 32);
    const unsigned short* kbase = kh + (size_t)bh * Sc * 64;
    const unsigned short* vbase = vt + (size_t)bh * 64 * Sc;

    const int kt0 = kh_ * 1024;

    // DMA stage: linear LDS dest (wave base + lane*16), inverse-swizzled
    // global source. Per kh-group: 8 KB = K 4KB (4 segs) + V 4KB (4 segs);
    // each of the group's 2 waves DMAs 2 K-segs + 2 V-segs of 1 KB.
    auto stage_tile = [&](int buf, int kt) {
        char* gb = (char*)smem4[buf] + kh_ * 8192;
#pragma unroll
        for (int c = 0; c < 2; ++c) {
            const int seg = wv * 2 + c;                  // wave-uniform
            const int s   = seg * 64 + lane;             // linear 16B slot
            const int r   = s >> 3, cc = (s & 7) ^ (r & 7);
            const unsigned short* gs = kbase + (size_t)(kt + r) * 64 + cc * 8;
            __builtin_amdgcn_global_load_lds(
                (const __attribute__((address_space(1))) unsigned int*)gs,
                (__attribute__((address_space(3))) unsigned int*)(gb + seg * 1024),
                16, 0, 0);
        }
        char* vb = gb + 4096;
#pragma unroll
        for (int c = 0; c < 2; ++c) {
            const int seg = wv * 2 + c;                  // = cc (chunk index)
            const int dv  = lane ^ (seg << 1);
            const unsigned short* gs = vbase + (size_t)dv * Sc + kt + seg * 8;
            __builtin_amdgcn_global_load_lds(
                (const __attribute__((address_space(1))) unsigned int*)gs,
                (__attribute__((address_space(3))) unsigned int*)(vb + seg * 1024),
                16, 0, 0);
        }
    };

    stage_tile(0, kt0);
    unsigned mwn = mr[kt0 >> 5];

    for (int i = 0; i < 32; ++i) {
        const int kt = kt0 + i * 32;
        const int buf = i & 1;
        __syncthreads();          // drains this wave's DMA (vmcnt) + orders buf reuse
        const unsigned mw = mwn;
        if (i < 31) {
            stage_tile(buf ^ 1, kt + 32);
            mwn = mr[(kt + 32) >> 5];
        }

        const unsigned short* Ks = (const unsigned short*)smem4[buf] + kh_ * 4096;
        const unsigned short* Vs = Ks + 2048;

        // ---- S^T[key][q] = K · Q^T
        f32x16 sv;
#pragma unroll
        for (int r = 0; r < 16; ++r) sv[r] = 0.f;
        __builtin_amdgcn_s_setprio(1);
#pragma unroll
        for (int kc = 0; kc < 4; ++kc) {
            s16x8 kf = *(const s16x8*)&Ks[ln * 64 + ((((kc << 1) | hf) ^ (ln & 7)) * 8)];
            sv = __builtin_amdgcn_mfma_f32_32x32x16_bf16(kf, qf[kc], sv, 0, 0, 0);
        }
        __builtin_amdgcn_s_setprio(0);

        // ---- mask + exp2 (no max: scores bounded), pack to bf16 pairs
        float ps = 0.f;
        unsigned pu[8];
#pragma unroll
        for (int r = 0; r < 16; r += 2) {
            int key0 = (r & 3) + 8 * (r >> 2) + 4 * hf;
            int key1 = ((r + 1) & 3) + 8 * ((r + 1) >> 2) + 4 * hf;
            float a0 = ((mw >> key0) & 1u) ? sv[r]     : -1e9f;
            float a1 = ((mw >> key1) & 1u) ? sv[r + 1] : -1e9f;
            float p0 = fexp2(a0), p1 = fexp2(a1);
            ps += p0 + p1;
            pu[r >> 1] = (unsigned)f2bf(p0) | ((unsigned)f2bf(p1) << 16);
        }
        lr += ps;

        // ---- ctx^T[dv][q] += V · P^T
        __builtin_amdgcn_s_setprio(1);
#pragma unroll
        for (int kc = 0; kc < 2; ++kc) {
            uint4 ua; ua.x = pu[4*kc]; ua.y = pu[4*kc+1]; ua.z = pu[4*kc+2]; ua.w = pu[4*kc+3];
            s16x8 pf = __builtin_bit_cast(s16x8, ua);
            const int cc = (kc << 1) | hf;
            s16x8 v0  = *(const s16x8*)&Vs[(cc * 64 + (ln ^ (cc << 1))) * 8];
            s16x8 v1  = *(const s16x8*)&Vs[(cc * 64 + ((32 + ln) ^ (cc << 1))) * 8];
            o0 = __builtin_amdgcn_mfma_f32_32x32x16_bf16(v0, pf, o0, 0, 0, 0);
            o1 = __builtin_amdgcn_mfma_f32_32x32x16_bf16(v1, pf, o1, 0, 0, 0);
        }
        __builtin_amdgcn_s_setprio(0);
    }

    // l per-hf partial -> full
    lr += __shfl_xor(lr, 32);

    // ---- cross-half combine (linear). kh=1 -> LDS, kh=0 adds + writes.
    // Region [128][48] f32 = 24576 B; float4 slot q stored at (q ^ (row&7)):
    // 8 lanes cover all 32 banks -> conflict-free.
    __syncthreads();
    float* cs = (float*)smem4[0];
    const int row = g * 64 + lane;
    float* my = cs + (size_t)row * 48;
    const int sw = lane & 7;
    if (kh_ == 1) {
#pragma unroll
        for (int r = 0; r < 4; ++r) {
            *(float4*)(my + ((r ^ sw) * 4))       = make_float4(o0[4*r], o0[4*r+1], o0[4*r+2], o0[4*r+3]);
            *(float4*)(my + (((r + 4) ^ sw) * 4)) = make_float4(o1[4*r], o1[4*r+1], o1[4*r+2], o1[4*r+3]);
        }
        my[32] = lr;
    }
    __syncthreads();
    if (kh_ == 0) {
        lr += my[32];
        const float inv = 1.f / lr;
#pragma unroll
        for (int r = 0; r < 4; ++r) {
            float4 a0 = *(const float4*)(my + ((r ^ sw) * 4));
            float4 a1 = *(const float4*)(my + (((r + 4) ^ sw) * 4));
            o0[4*r]   = (o0[4*r]   + a0.x) * inv; o0[4*r+1] = (o0[4*r+1] + a0.y) * inv;
            o0[4*r+2] = (o0[4*r+2] + a0.z) * inv; o0[4*r+3] = (o0[4*r+3] + a0.w) * inv;
            o1[4*r]   = (o1[4*r]   + a1.x) * inv; o1[4*r+1] = (o1[4*r+1] + a1.y) * inv;
            o1[4*r+2] = (o1[4*r+2] + a1.z) * inv; o1[4*r+3] = (o1[4*r+3] + a1.w) * inv;
        }
        // ctx bf16 [B,S,D]; dv = 8*gg + 4*hf + t (+32 for the o1 half)
        unsigned short* op = ctx + ((size_t)(b * Sc + qr)) * 512 + h * 64;
#pragma unroll
        for (int gg = 0; gg < 4; ++gg) {
            ushort4 a, c;
            a.x = f2bf(o0[gg*4+0]); a.y = f2bf(o0[gg*4+1]);
            a.z = f2bf(o0[gg*4+2]); a.w = f2bf(o0[gg*4+3]);
            c.x = f2bf(o1[gg*4+0]); c.y = f2bf(o1[gg*4+1]);
            c.z = f2bf(o1[gg*4+2]); c.w = f2bf(o1[gg*4+3]);
            *(ushort4*)(op + 8 * gg + 4 * hf)      = a;
            *(ushort4*)(op + 32 + 8 * gg + 4 * hf) = c;
        }
    }
}

// ---------------------------------------------------------------------------
extern "C" void kernel_launch(void* const* d_in, const int* in_sizes, int n_in,
                              void* d_out, int out_size, void* d_ws, size_t ws_size,
                              hipStream_t stream)
{
    (void)in_sizes; (void)n_in; (void)out_size; (void)ws_size;

    const float* q    = (const float*)d_in[0];
    const float* k    = (const float*)d_in[1];
    const float* v    = (const float*)d_in[2];
    const int*   mask = (const int*)  d_in[3];
    const float* Wq   = (const float*)d_in[4];
    const float* bq   = (const float*)d_in[5];
    const float* Wk   = (const float*)d_in[6];
    const float* bk   = (const float*)d_in[7];
    const float* Wv   = (const float*)d_in[8];
    const float* bv   = (const float*)d_in[9];
    const float* Wo   = (const float*)d_in[10];
    const float* bo   = (const float*)d_in[11];
    float* out = (float*)d_out;

    // workspace carve; TEN = 4,194,304 elems
    constexpr size_t TEN = (size_t)Bc * Hc * Sc * DKc;
    char* p = (char*)d_ws;
    unsigned short* wqb   = (unsigned short*)p;  p += (size_t)Dc * Dc * 2;  // 0.5 MB
    unsigned short* wkb   = (unsigned short*)p;  p += (size_t)Dc * Dc * 2;
    unsigned short* wvb   = (unsigned short*)p;  p += (size_t)Dc * Dc * 2;
    unsigned short* wob   = (unsigned short*)p;  p += (size_t)Dc * Dc * 2;
    unsigned short* qh_bf = (unsigned short*)p;  p += TEN * 2;              // 8 MB
    unsigned short* kh_bf = (unsigned short*)p;  p += TEN * 2;
    unsigned short* vt_bf = (unsigned short*)p;  p += TEN * 2;
    unsigned short* ctx   = (unsigned short*)p;  p += TEN * 2;
    unsigned long long* mb64 = (unsigned long long*)p;                      // 2 MB

    // bf16 copies of q,k,v — ZERO workspace cost via aliasing:
    //   qb,kb live in d_out (16 MB, dead until the final GEMM writes it);
    //   vb lives in ctx (written only later, by attn, after QKV reads vb).
    unsigned short* qb = (unsigned short*)d_out;
    unsigned short* kb = qb + TEN;
    unsigned short* vb = ctx;

    const int nwords = Bc * Sc * (Sc / 64);   // 262144

    dim3 bb(256);

    pack_mask<<<dim3(16384), bb, 0, stream>>>(mask, mb64, nwords);
    // weights fp32->bf16 (4 tensors, 64K float4s each)
    cvt4<<<dim3(Dc * Dc / 4 / 256, 4), bb, 0, stream>>>(Wq, Wk, Wv, Wo, wqb, wkb, wvb, wob,
                                                        Dc * Dc / 4);
    // activations fp32->bf16 (3 tensors, 1M float4s each)
    cvt4<<<dim3((int)(TEN / 4 / 256), 3), bb, 0, stream>>>(q, k, v, v, qb, kb, vb, vb,
                                                           (int)(TEN / 4));
    // merged Q/K/V projections: one dispatch, 1536 blocks, 3 blocks/CU
    gemm128<<<dim3(Mc / 128, Dc / 64, 3), bb, 0, stream>>>(
        qb, kb, vb, wqb, wkb, wvb, bq, bk, bv, qh_bf, kh_bf, vt_bf,
        SCALE_Q, 1.0f, 1.0f, 1, 1, 2);
    attn_mfma<<<dim3(Sc / 64, Bc * Hc), bb, 0, stream>>>(qh_bf, kh_bf, vt_bf,
                                                         (const unsigned*)mb64, ctx);
    gemm128<<<dim3(Mc / 128, Dc / 64, 1), bb, 0, stream>>>(
        ctx, ctx, ctx, wob, wob, wob, bo, bo, bo, out, out, out,
        1.0f, 1.0f, 1.0f, 0, 0, 0);
}